// Round 9
// baseline (49.937 us; speedup 1.0000x reference)
//
#include <hip/hip_runtime.h>
#include <math.h>

// BalNoisedTopK: loss = mean_i relu(1 + mean_j kth_max(s_i + Z_ij, excl y_i) - s_{i,y_i})
// s: (n, d) f32, y: (n,) i32, Z: (n, d, m) f32 (m innermost), out: scalar f32.
// K=5, m=8, eps=1.0 compile-time constants per the reference.
//
// Two kernels. Stage 1 (R7 structure, proven 44.2us): dword Z loads (two
// widening attempts R6/R8 were neutral/worse -> stream is at the ~6.3TB/s
// mixed HBM+LLC ceiling), s-chunk staged in LDS. Stage 2: one block per row
// merges chunk candidates; batch mean fused via deterministic int64
// fixed-point atomics (64 single-thread atomics; NOT R5's 2048 block-wide
// fences which caused L2-invalidate collapse).

#define KTOP 5
#define MSAMP 8
#define TPB 256
#define NCHUNKS 32
#define SLDS 3200   // max staged chunk elements (nchunks=32 -> chunk=3136)
#define FIXSCALE 4194304.0f   // 2^22 fixed-point scale for the loss sum

// v sorted ascending; v[0] = current 5th-largest. Branchless insert:
// new v[q] = median(x, v[q], v[q+1]) == clamp(x, v[q], v[q+1]) since v sorted.
__device__ __forceinline__ void topk_insert_bl(float (&v)[KTOP], float x) {
    float n0 = __builtin_amdgcn_fmed3f(x, v[0], v[1]);
    float n1 = __builtin_amdgcn_fmed3f(x, v[1], v[2]);
    float n2 = __builtin_amdgcn_fmed3f(x, v[2], v[3]);
    float n3 = __builtin_amdgcn_fmed3f(x, v[3], v[4]);
    float n4 = fmaxf(v[4], x);
    v[0] = n0; v[1] = n1; v[2] = n2; v[3] = n3; v[4] = n4;
}

__global__ __launch_bounds__(TPB) void topk_partial(
    const float* __restrict__ s, const int* __restrict__ y,
    const float* __restrict__ Z, float* __restrict__ cand,
    int d, int nchunks, int chunk)
{
    const int i = blockIdx.x / nchunks;
    const int c = blockIdx.x % nchunks;
    const int e0 = c * chunk;                 // chunk is 32-aligned
    const int e1 = min(e0 + chunk, d);
    const int yi = y[i];

    const int t = threadIdx.x;
    const int j = t & 7;          // sample owned by this lane
    const int eofs = t >> 3;      // 0..31: element offset within block stride

    const float* __restrict__ srow = s + (size_t)i * d;
    const float* __restrict__ zrow = Z + (size_t)i * d * MSAMP;

    __shared__ __align__(16) float s_lds[SLDS];
    const int clen = e1 - e0;
    {
        const int nv4 = clen > 0 ? (clen >> 2) : 0;
        for (int w = t; w < nv4; w += TPB) {  // srow+e0 is 128B-aligned
            float4 vv = *(const float4*)(srow + e0 + (size_t)w * 4);
            *(float4*)(s_lds + w * 4) = vv;
        }
        for (int w = (nv4 << 2) + t; w < clen; w += TPB)
            s_lds[w] = srow[e0 + w];
        __syncthreads();
    }

    float v[KTOP];
    #pragma unroll
    for (int q = 0; q < KTOP; ++q) v[q] = -INFINITY;

    // Block covers 32 elements x 8 samples per iteration; the wave's 64 Z
    // loads are one aligned 256B segment. s comes from LDS (8-lane broadcast).
    #pragma unroll 8
    for (int e = e0 + eofs; e < e1; e += 32) {
        float sv = s_lds[e - e0];
        float z  = zrow[(size_t)e * MSAMP + j];
        float x  = (e == yi) ? -INFINITY : (sv + z);
        topk_insert_bl(v, x);
    }

    // Butterfly merge across the 8 lanes that share sample j (xor 8/16/32
    // preserves t&7). Afterwards every lane holds its wave's per-sample top5.
    #pragma unroll
    for (int off = 8; off <= 32; off <<= 1) {
        float o[KTOP];
        #pragma unroll
        for (int q = 0; q < KTOP; ++q) o[q] = __shfl_xor(v[q], off, 64);
        #pragma unroll
        for (int q = 0; q < KTOP; ++q) topk_insert_bl(v, o[q]);
    }

    __shared__ float lds[TPB / 64][MSAMP][KTOP];
    const int wave = t >> 6;
    const int lane = t & 63;
    if (lane < MSAMP) {
        #pragma unroll
        for (int q = 0; q < KTOP; ++q) lds[wave][lane][q] = v[q];
    }
    __syncthreads();

    if (t < MSAMP) {
        float f[KTOP];
        #pragma unroll
        for (int q = 0; q < KTOP; ++q) f[q] = lds[0][t][q];
        #pragma unroll
        for (int w = 1; w < TPB / 64; ++w)
            #pragma unroll
            for (int q = 0; q < KTOP; ++q) topk_insert_bl(f, lds[w][t][q]);
        float* out = cand + (((size_t)i * nchunks + c) * MSAMP + t) * KTOP;
        #pragma unroll
        for (int q = 0; q < KTOP; ++q) out[q] = f[q];
    }
}

// One block per row i. Merges chunk candidates (butterfly over c within wave,
// LDS across waves), averages kth over samples, then contributes the row's
// hinge loss to a global int64 fixed-point sum (deterministic: llrintf is
// exact per row, integer addition is order-independent). The last block to
// increment the counter (acq_rel; acquires all 63 prior releases) writes the
// batch mean to out[0].
__global__ __launch_bounds__(TPB) void row_loss(
    const float* __restrict__ s, const int* __restrict__ y,
    const float* __restrict__ cand, float* __restrict__ out,
    unsigned long long* __restrict__ fsum, int* __restrict__ cnt,
    int n, int d, int nchunks)
{
    const int i = blockIdx.x;
    const int t = threadIdx.x;
    const int j = t & 7;
    const int wave = t >> 6;
    const int lane = t & 63;

    float v[KTOP];
    #pragma unroll
    for (int q = 0; q < KTOP; ++q) v[q] = -INFINITY;

    for (int c = t >> 3; c < nchunks; c += TPB / MSAMP) {
        const float* p = cand + (((size_t)i * nchunks + c) * MSAMP + j) * KTOP;
        #pragma unroll
        for (int q = 0; q < KTOP; ++q) topk_insert_bl(v, p[q]);
    }

    // Merge across the 8 chunk-slots sharing sample j inside this wave.
    #pragma unroll
    for (int off = 8; off <= 32; off <<= 1) {
        float o[KTOP];
        #pragma unroll
        for (int q = 0; q < KTOP; ++q) o[q] = __shfl_xor(v[q], off, 64);
        #pragma unroll
        for (int q = 0; q < KTOP; ++q) topk_insert_bl(v, o[q]);
    }

    __shared__ float lds[TPB / 64][MSAMP][KTOP];
    __shared__ float kth_j[MSAMP];
    if (lane < MSAMP) {
        #pragma unroll
        for (int q = 0; q < KTOP; ++q) lds[wave][lane][q] = v[q];
    }
    __syncthreads();

    if (t < MSAMP) {
        float f[KTOP];
        #pragma unroll
        for (int q = 0; q < KTOP; ++q) f[q] = lds[0][t][q];
        #pragma unroll
        for (int w = 1; w < TPB / 64; ++w)
            #pragma unroll
            for (int q = 0; q < KTOP; ++q) topk_insert_bl(f, lds[w][t][q]);
        kth_j[t] = f[0];                 // exact 5th-largest for (i, j=t)
    }
    __syncthreads();

    if (t == 0) {
        float sum = 0.0f;
        #pragma unroll
        for (int jj = 0; jj < MSAMP; ++jj) sum += kth_j[jj];
        float kth_smooth = sum * (1.0f / (float)MSAMP);
        float sy = s[(size_t)i * d + y[i]];
        float loss = fmaxf(1.0f + kth_smooth - sy, 0.0f);

        // Deterministic fixed-point contribution (loss >= 0, bounded ~O(10)).
        unsigned long long fx = (unsigned long long)llrintf(loss * FIXSCALE);
        __hip_atomic_fetch_add(fsum, fx, __ATOMIC_RELAXED,
                               __HIP_MEMORY_SCOPE_AGENT);
        int old = __hip_atomic_fetch_add(cnt, 1, __ATOMIC_ACQ_REL,
                                         __HIP_MEMORY_SCOPE_AGENT);
        if (old == n - 1) {              // last row: all fsum adds visible
            unsigned long long total = __hip_atomic_load(
                fsum, __ATOMIC_RELAXED, __HIP_MEMORY_SCOPE_AGENT);
            out[0] = (float)((double)total / (double)FIXSCALE) / (float)n;
        }
    }
}

extern "C" void kernel_launch(void* const* d_in, const int* in_sizes, int n_in,
                              void* d_out, int out_size, void* d_ws, size_t ws_size,
                              hipStream_t stream) {
    const float* s = (const float*)d_in[0];
    const int*   y = (const int*)d_in[1];
    const float* Z = (const float*)d_in[2];
    float* out = (float*)d_out;

    const int n = in_sizes[1];
    const int d = in_sizes[0] / n;

    // ws layout: [fsum: u64][cnt: int + pad to 256B][cand]
    char* ws = (char*)d_ws;
    unsigned long long* fsum = (unsigned long long*)ws;
    int* cnt = (int*)(ws + 8);
    float* cand = (float*)(ws + 256);

    int nchunks = NCHUNKS;
    while (nchunks > 1 &&
           256 + (size_t)n * nchunks * MSAMP * KTOP * sizeof(float) > ws_size) {
        nchunks >>= 1;
    }
    int chunk = (d + nchunks - 1) / nchunks;
    chunk = (chunk + 31) & ~31;           // 32-aligned -> aligned Z segments

    hipMemsetAsync(ws, 0, 16, stream);    // zero fsum + cnt (capture-legal)
    hipLaunchKernelGGL(topk_partial, dim3(n * nchunks), dim3(TPB), 0, stream,
                       s, y, Z, cand, d, nchunks, chunk);
    hipLaunchKernelGGL(row_loss, dim3(n), dim3(TPB), 0, stream,
                       s, y, cand, out, fsum, cnt, n, d, nchunks);
}